// Round 2
// baseline (320.798 us; speedup 1.0000x reference)
//
#include <hip/hip_runtime.h>

// TensorProductContraction: fused irrep-linear + Clebsch-Gordan re-expansion.
// Phase 1 (prep_kernel): pack x -> 12 bf16 A-panels (component-separated) and
// w -> 4 bf16 B-panels, both in exact mfma_f32_16x16x32_bf16 fragment lane
// order, into d_ws (26.7 MB needed).
// Phase 2 (tp_main): per-wave 32Mx16V tile, K=128 (4 MFMA k-steps), 12 (v<1024)
// or 4 (v>=1024) accumulators, in-register CG mix, scatter-store f32 output.
// Round 1 fix: reference's cg(1,1,1) sign (SVD argmax tie on +-1/sqrt(6)
// entries) came out as -eps; negate the six antisymmetric contributions.

typedef __attribute__((ext_vector_type(8))) __bf16 bf16x8;
typedef __attribute__((ext_vector_type(8))) unsigned short u16x8;
typedef __attribute__((ext_vector_type(4))) float f32x4;

#define A_V8_TOTAL (12 * 512 * 4 * 64)  // 1,572,864 u16x8 (16B) entries = 25.2 MB
#define B_V8_TOTAL (384 * 4 * 64)       // 98,304 entries = 1.57 MB
#define P_STRIDE   (512 * 4 * 64)       // 131072 u16x8 per A panel
#define WS_NEED_BYTES ((size_t)(A_V8_TOTAL + B_V8_TOTAL) * 16)

__device__ __forceinline__ unsigned short f2bf(float f) {
  unsigned u = __builtin_bit_cast(unsigned, f);
  u = (u + 0x7FFFu + ((u >> 16) & 1u)) >> 16;  // RNE
  return (unsigned short)u;
}

__device__ __forceinline__ f32x4 mfma16(bf16x8 a, bf16x8 b, f32x4 c) {
  return __builtin_amdgcn_mfma_f32_16x16x32_bf16(a, b, c, 0, 0, 0);
}
__device__ __forceinline__ bf16x8 asbf(u16x8 v) { return __builtin_bit_cast(bf16x8, v); }

// ---------------- prep: f32 -> bf16 fragment-packed panels ----------------
// A panel p in [0,12): {0e.0, 1o.0,1o.1,1o.2, 1e.0,1e.1,1e.2, 2e.0..4}
// A[p][mt(512)][kb(4)][lane(64)] : element = x[m=mt*16+(l&15), col(k=kb*32+(l>>4)*8+e)]
// B panel ci in [0,384): 0e:0..127, 1o:128..255, 1e:256..319, 2e:320..383
// B[ci][kb][lane] : element = w_seg[u=kb*32+(l>>4)*8+e, v=ci_local*16+(l&15)]
__global__ __launch_bounds__(256) void prep_kernel(
    const float* __restrict__ x, const float* __restrict__ w0e,
    const float* __restrict__ w1o, const float* __restrict__ w1e,
    const float* __restrict__ w2e, u16x8* __restrict__ ws) {
  int t = blockIdx.x * 256 + threadIdx.x;
  if (t < A_V8_TOTAL) {
    int l = t & 63;
    int kb = (t >> 6) & 3;
    int mt = (t >> 8) & 511;
    int p = t >> 17;
    int m = mt * 16 + (l & 15);
    int k0 = kb * 32 + (l >> 4) * 8;
    int base, d, comp;
    if (p == 0)      { base = 0;   d = 1; comp = 0;     }
    else if (p < 4)  { base = 128; d = 3; comp = p - 1; }
    else if (p < 7)  { base = 512; d = 3; comp = p - 4; }
    else             { base = 896; d = 5; comp = p - 7; }
    const float* xr = x + (size_t)m * 1536 + base + comp + k0 * d;
    u16x8 v;
#pragma unroll
    for (int e = 0; e < 8; ++e) v[e] = f2bf(xr[e * d]);
    ws[t] = v;
  } else {
    int tb = t - A_V8_TOTAL;
    if (tb >= B_V8_TOTAL) return;
    int l = tb & 63;
    int kb = (tb >> 6) & 3;
    int ci = tb >> 8;
    const float* w; int N, v0;
    if (ci < 128)      { w = w0e; N = 2048; v0 = ci * 16;         }
    else if (ci < 256) { w = w1o; N = 2048; v0 = (ci - 128) * 16; }
    else if (ci < 320) { w = w1e; N = 1024; v0 = (ci - 256) * 16; }
    else               { w = w2e; N = 1024; v0 = (ci - 320) * 16; }
    int n = v0 + (l & 15);
    int k0 = kb * 32 + (l >> 4) * 8;
    u16x8 v;
#pragma unroll
    for (int e = 0; e < 8; ++e) v[e] = f2bf(w[(size_t)(k0 + e) * N + n]);
    ws[A_V8_TOTAL + tb] = v;
  }
}

// ---------------- main fused kernel ----------------
// wave tile: 32 M-rows (2 Mfrags) x 16 v-cols. vt in [0,64): region L (12 panels),
// vt in [64,128): region H (4 panels). Block = 4 waves, same vt, 4 consecutive mt2.
__global__ __launch_bounds__(256) void tp_main(const u16x8* __restrict__ ws,
                                               float* __restrict__ out) {
  const int l = threadIdx.x & 63;
  const int wv = threadIdx.x >> 6;
  const int vt = blockIdx.x >> 6;                  // 0..127
  const int mt2 = ((blockIdx.x & 63) << 2) | wv;   // 0..255 (32-row tiles)
  const int l15 = l & 15, lhi = l >> 4;
  const u16x8* Ap = ws;
  const u16x8* Bp = ws + A_V8_TOTAL;

  const float c3  = 0.57735026918962576f;   // 1/sqrt(3)
  const float c6  = 0.40824829046386302f;   // 1/sqrt(6)
  const float c10 = 0.31622776601683794f;   // 1/sqrt(10)
  const float c30 = 0.18257418583505537f;   // 1/sqrt(30)

  if (vt < 64) {
    // ---- region L: y0[v], y1o[v,0:3], y1e[v,0:3], y2e[v,0:5] -> C + D blocks
    f32x4 acc[2][12];
#pragma unroll
    for (int mf = 0; mf < 2; ++mf)
#pragma unroll
      for (int p = 0; p < 12; ++p) acc[mf][p] = (f32x4)(0.0f);

    const int ci0 = vt, ci1 = 128 + vt, ci2 = 256 + vt, ci3 = 320 + vt;
#pragma unroll
    for (int kb = 0; kb < 4; ++kb) {
      bf16x8 b0 = asbf(Bp[((ci0 << 2) + kb) * 64 + l]);
      bf16x8 b1 = asbf(Bp[((ci1 << 2) + kb) * 64 + l]);
      bf16x8 b2 = asbf(Bp[((ci2 << 2) + kb) * 64 + l]);
      bf16x8 b3 = asbf(Bp[((ci3 << 2) + kb) * 64 + l]);
#pragma unroll
      for (int mf = 0; mf < 2; ++mf) {
        const u16x8* ar = Ap + (((((mt2 << 1) | mf) << 2) + kb) << 6) + l;
        acc[mf][0]  = mfma16(asbf(ar[0]),             b0, acc[mf][0]);
        acc[mf][1]  = mfma16(asbf(ar[1 * P_STRIDE]),  b1, acc[mf][1]);
        acc[mf][2]  = mfma16(asbf(ar[2 * P_STRIDE]),  b1, acc[mf][2]);
        acc[mf][3]  = mfma16(asbf(ar[3 * P_STRIDE]),  b1, acc[mf][3]);
        acc[mf][4]  = mfma16(asbf(ar[4 * P_STRIDE]),  b2, acc[mf][4]);
        acc[mf][5]  = mfma16(asbf(ar[5 * P_STRIDE]),  b2, acc[mf][5]);
        acc[mf][6]  = mfma16(asbf(ar[6 * P_STRIDE]),  b2, acc[mf][6]);
        acc[mf][7]  = mfma16(asbf(ar[7 * P_STRIDE]),  b3, acc[mf][7]);
        acc[mf][8]  = mfma16(asbf(ar[8 * P_STRIDE]),  b3, acc[mf][8]);
        acc[mf][9]  = mfma16(asbf(ar[9 * P_STRIDE]),  b3, acc[mf][9]);
        acc[mf][10] = mfma16(asbf(ar[10 * P_STRIDE]), b3, acc[mf][10]);
        acc[mf][11] = mfma16(asbf(ar[11 * P_STRIDE]), b3, acc[mf][11]);
      }
    }
    // epilogue: CG mix + scatter. v = vt*16 + l15; C idx = 4096+(v>>5)*96+lam*32+(v&31)
    // D idx = 7168+(v>>5)*288 + lam*96 + (v&31)*3 + rho
    const int v5 = vt >> 1;
    const int v31 = ((vt & 1) << 4) | l15;
#pragma unroll
    for (int mf = 0; mf < 2; ++mf) {
#pragma unroll
      for (int j = 0; j < 4; ++j) {
        const int m = mt2 * 32 + mf * 16 + lhi * 4 + j;
        float* orow = out + (size_t)m * 16384;
        float* oc = orow + 4096 + v5 * 96 + v31;
        oc[0]  = acc[mf][1][j] * c3;
        oc[32] = acc[mf][2][j] * c3;
        oc[64] = acc[mf][3][j] * c3;
        const float s  = acc[mf][0][j] * c3;
        const float e0 = acc[mf][4][j], e1 = acc[mf][5][j], e2 = acc[mf][6][j];
        const float q0 = acc[mf][7][j], q1 = acc[mf][8][j];
        const float q2 = acc[mf][9][j], q3 = acc[mf][10][j], q4 = acc[mf][11][j];
        float* od = orow + 7168 + v5 * 288 + v31 * 3;
        // cg(1,1,1) = -eps/sqrt(6) (reference SVD sign); symmetric terms unchanged
        od[0]   = s - q2 * c30 - q4 * c10;     // D[0][0]
        od[1]   = -e2 * c6 + q1 * c10;         // D[0][1]
        od[2]   = e1 * c6 + q0 * c10;          // D[0][2]
        od[96]  = e2 * c6 + q1 * c10;          // D[1][0]
        od[97]  = s + 2.0f * q2 * c30;         // D[1][1]
        od[98]  = -e0 * c6 + q3 * c10;         // D[1][2]
        od[192] = -e1 * c6 + q0 * c10;         // D[2][0]
        od[193] = e0 * c6 + q3 * c10;          // D[2][1]
        od[194] = s - q2 * c30 + q4 * c10;     // D[2][2]
      }
    }
  } else {
    // ---- region H: v' = v-1024; y0[v] -> A block, y1o[v,:] -> B block
    const int vtp = vt - 64;
    f32x4 acc[2][4];
#pragma unroll
    for (int mf = 0; mf < 2; ++mf)
#pragma unroll
      for (int p = 0; p < 4; ++p) acc[mf][p] = (f32x4)(0.0f);

    const int ci0 = 64 + vtp, ci1 = 192 + vtp;
#pragma unroll
    for (int kb = 0; kb < 4; ++kb) {
      bf16x8 b0 = asbf(Bp[((ci0 << 2) + kb) * 64 + l]);
      bf16x8 b1 = asbf(Bp[((ci1 << 2) + kb) * 64 + l]);
#pragma unroll
      for (int mf = 0; mf < 2; ++mf) {
        const u16x8* ar = Ap + (((((mt2 << 1) | mf) << 2) + kb) << 6) + l;
        acc[mf][0] = mfma16(asbf(ar[0]),            b0, acc[mf][0]);
        acc[mf][1] = mfma16(asbf(ar[1 * P_STRIDE]), b1, acc[mf][1]);
        acc[mf][2] = mfma16(asbf(ar[2 * P_STRIDE]), b1, acc[mf][2]);
        acc[mf][3] = mfma16(asbf(ar[3 * P_STRIDE]), b1, acc[mf][3]);
      }
    }
    const int vp = vtp * 16 + l15;
#pragma unroll
    for (int mf = 0; mf < 2; ++mf) {
#pragma unroll
      for (int j = 0; j < 4; ++j) {
        const int m = mt2 * 32 + mf * 16 + lhi * 4 + j;
        float* orow = out + (size_t)m * 16384;
        orow[vp] = acc[mf][0][j];               // A block (cg = 1)
        float* ob = orow + 1024 + vp * 3;       // B block
        ob[0] = acc[mf][1][j] * c3;
        ob[1] = acc[mf][2][j] * c3;
        ob[2] = acc[mf][3][j] * c3;
      }
    }
  }
}

extern "C" void kernel_launch(void* const* d_in, const int* in_sizes, int n_in,
                              void* d_out, int out_size, void* d_ws, size_t ws_size,
                              hipStream_t stream) {
  if (ws_size < WS_NEED_BYTES) return;  // need 26.7 MB scratch; fail visibly if absent
  const float* x   = (const float*)d_in[0];
  const float* w0e = (const float*)d_in[1];
  const float* w1o = (const float*)d_in[2];
  const float* w1e = (const float*)d_in[3];
  const float* w2e = (const float*)d_in[4];
  u16x8* ws = (u16x8*)d_ws;
  float* out = (float*)d_out;

  // prep: (A_V8_TOTAL + B_V8_TOTAL) threads = 1,671,168 = 6528 * 256 exactly
  prep_kernel<<<6528, 256, 0, stream>>>(x, w0e, w1o, w1e, w2e, ws);
  // main: 256 mt2-tiles * 128 vt-tiles = 32768 waves = 8192 blocks of 4 waves
  tp_main<<<8192, 256, 0, stream>>>(ws, out);
}

// Round 3
// 175.697 us; speedup vs baseline: 1.8259x; 1.8259x over previous
//
#include <hip/hip_runtime.h>

// TensorProductContraction: fused irrep-linear + Clebsch-Gordan re-expansion.
// Phase 1 (prep_kernel): pack x -> 12 bf16 A-panels (component-separated) and
// w -> 4 bf16 B-panels, in mfma_f32_16x16x32_bf16 fragment lane order (26.7 MB ws).
// Phase 2 (tp_main): per-wave 32Mx16V tile, K=128, 12 (v<1024) or 4 (v>=1024)
// accumulators, in-register CG mix, non-temporal scatter stores.
// Round 3: block remap so all 4 waves share one mt2 A-slice, XCD-chunked
// bijective swizzle (A re-reads become L1/L2 hits), nt stores to keep the
// 512 MB output stream from thrashing L2. Inner compute identical to round 2.

typedef __attribute__((ext_vector_type(8))) __bf16 bf16x8;
typedef __attribute__((ext_vector_type(8))) unsigned short u16x8;
typedef __attribute__((ext_vector_type(4))) float f32x4;

#define A_V8_TOTAL (12 * 512 * 4 * 64)  // 1,572,864 u16x8 (16B) entries = 25.2 MB
#define B_V8_TOTAL (384 * 4 * 64)       // 98,304 entries = 1.57 MB
#define P_STRIDE   (512 * 4 * 64)       // 131072 u16x8 per A panel
#define WS_NEED_BYTES ((size_t)(A_V8_TOTAL + B_V8_TOTAL) * 16)

__device__ __forceinline__ unsigned short f2bf(float f) {
  unsigned u = __builtin_bit_cast(unsigned, f);
  u = (u + 0x7FFFu + ((u >> 16) & 1u)) >> 16;  // RNE
  return (unsigned short)u;
}

__device__ __forceinline__ f32x4 mfma16(bf16x8 a, bf16x8 b, f32x4 c) {
  return __builtin_amdgcn_mfma_f32_16x16x32_bf16(a, b, c, 0, 0, 0);
}
__device__ __forceinline__ bf16x8 asbf(u16x8 v) { return __builtin_bit_cast(bf16x8, v); }
__device__ __forceinline__ void stnt(float* p, float v) { __builtin_nontemporal_store(v, p); }

// ---------------- prep: f32 -> bf16 fragment-packed panels ----------------
__global__ __launch_bounds__(256) void prep_kernel(
    const float* __restrict__ x, const float* __restrict__ w0e,
    const float* __restrict__ w1o, const float* __restrict__ w1e,
    const float* __restrict__ w2e, u16x8* __restrict__ ws) {
  int t = blockIdx.x * 256 + threadIdx.x;
  if (t < A_V8_TOTAL) {
    int l = t & 63;
    int kb = (t >> 6) & 3;
    int mt = (t >> 8) & 511;
    int p = t >> 17;
    int m = mt * 16 + (l & 15);
    int k0 = kb * 32 + (l >> 4) * 8;
    int base, d, comp;
    if (p == 0)      { base = 0;   d = 1; comp = 0;     }
    else if (p < 4)  { base = 128; d = 3; comp = p - 1; }
    else if (p < 7)  { base = 512; d = 3; comp = p - 4; }
    else             { base = 896; d = 5; comp = p - 7; }
    const float* xr = x + (size_t)m * 1536 + base + comp + k0 * d;
    u16x8 v;
#pragma unroll
    for (int e = 0; e < 8; ++e) v[e] = f2bf(xr[e * d]);
    ws[t] = v;
  } else {
    int tb = t - A_V8_TOTAL;
    if (tb >= B_V8_TOTAL) return;
    int l = tb & 63;
    int kb = (tb >> 6) & 3;
    int ci = tb >> 8;
    const float* w; int N, v0;
    if (ci < 128)      { w = w0e; N = 2048; v0 = ci * 16;         }
    else if (ci < 256) { w = w1o; N = 2048; v0 = (ci - 128) * 16; }
    else if (ci < 320) { w = w1e; N = 1024; v0 = (ci - 256) * 16; }
    else               { w = w2e; N = 1024; v0 = (ci - 320) * 16; }
    int n = v0 + (l & 15);
    int k0 = kb * 32 + (l >> 4) * 8;
    u16x8 v;
#pragma unroll
    for (int e = 0; e < 8; ++e) v[e] = f2bf(w[(size_t)(k0 + e) * N + n]);
    ws[A_V8_TOTAL + tb] = v;
  }
}

// ---------------- main fused kernel ----------------
// Block = 4 waves sharing one mt2 (32-row A-slice, L1-broadcast), each wave a
// different vt. Logical block order: vtb fastest within mt2; XCD-chunked swizzle.
__global__ __launch_bounds__(256) void tp_main(const u16x8* __restrict__ ws,
                                               float* __restrict__ out) {
  const int l = threadIdx.x & 63;
  const int wv = threadIdx.x >> 6;
  const int bid = blockIdx.x;
  const int logical = (bid & 7) * 1024 + (bid >> 3);  // 8192 blocks, bijective
  const int mt2 = logical >> 5;                       // 0..255 (32-row tiles)
  const int vt = ((logical & 31) << 2) | wv;          // 0..127
  const int l15 = l & 15, lhi = l >> 4;
  const u16x8* Ap = ws;
  const u16x8* Bp = ws + A_V8_TOTAL;

  const float c3  = 0.57735026918962576f;   // 1/sqrt(3)
  const float c6  = 0.40824829046386302f;   // 1/sqrt(6)
  const float c10 = 0.31622776601683794f;   // 1/sqrt(10)
  const float c30 = 0.18257418583505537f;   // 1/sqrt(30)

  if (vt < 64) {
    // ---- region L: y0[v], y1o[v,0:3], y1e[v,0:3], y2e[v,0:5] -> C + D blocks
    f32x4 acc[2][12];
#pragma unroll
    for (int mf = 0; mf < 2; ++mf)
#pragma unroll
      for (int p = 0; p < 12; ++p) acc[mf][p] = (f32x4)(0.0f);

    const int ci0 = vt, ci1 = 128 + vt, ci2 = 256 + vt, ci3 = 320 + vt;
#pragma unroll
    for (int kb = 0; kb < 4; ++kb) {
      bf16x8 b0 = asbf(Bp[((ci0 << 2) + kb) * 64 + l]);
      bf16x8 b1 = asbf(Bp[((ci1 << 2) + kb) * 64 + l]);
      bf16x8 b2 = asbf(Bp[((ci2 << 2) + kb) * 64 + l]);
      bf16x8 b3 = asbf(Bp[((ci3 << 2) + kb) * 64 + l]);
#pragma unroll
      for (int mf = 0; mf < 2; ++mf) {
        const u16x8* ar = Ap + (((((mt2 << 1) | mf) << 2) + kb) << 6) + l;
        acc[mf][0]  = mfma16(asbf(ar[0]),             b0, acc[mf][0]);
        acc[mf][1]  = mfma16(asbf(ar[1 * P_STRIDE]),  b1, acc[mf][1]);
        acc[mf][2]  = mfma16(asbf(ar[2 * P_STRIDE]),  b1, acc[mf][2]);
        acc[mf][3]  = mfma16(asbf(ar[3 * P_STRIDE]),  b1, acc[mf][3]);
        acc[mf][4]  = mfma16(asbf(ar[4 * P_STRIDE]),  b2, acc[mf][4]);
        acc[mf][5]  = mfma16(asbf(ar[5 * P_STRIDE]),  b2, acc[mf][5]);
        acc[mf][6]  = mfma16(asbf(ar[6 * P_STRIDE]),  b2, acc[mf][6]);
        acc[mf][7]  = mfma16(asbf(ar[7 * P_STRIDE]),  b3, acc[mf][7]);
        acc[mf][8]  = mfma16(asbf(ar[8 * P_STRIDE]),  b3, acc[mf][8]);
        acc[mf][9]  = mfma16(asbf(ar[9 * P_STRIDE]),  b3, acc[mf][9]);
        acc[mf][10] = mfma16(asbf(ar[10 * P_STRIDE]), b3, acc[mf][10]);
        acc[mf][11] = mfma16(asbf(ar[11 * P_STRIDE]), b3, acc[mf][11]);
      }
    }
    const int v5 = vt >> 1;
    const int v31 = ((vt & 1) << 4) | l15;
#pragma unroll
    for (int mf = 0; mf < 2; ++mf) {
#pragma unroll
      for (int j = 0; j < 4; ++j) {
        const int m = mt2 * 32 + mf * 16 + lhi * 4 + j;
        float* orow = out + (size_t)m * 16384;
        float* oc = orow + 4096 + v5 * 96 + v31;
        stnt(oc + 0,  acc[mf][1][j] * c3);
        stnt(oc + 32, acc[mf][2][j] * c3);
        stnt(oc + 64, acc[mf][3][j] * c3);
        const float s  = acc[mf][0][j] * c3;
        const float e0 = acc[mf][4][j], e1 = acc[mf][5][j], e2 = acc[mf][6][j];
        const float q0 = acc[mf][7][j], q1 = acc[mf][8][j];
        const float q2 = acc[mf][9][j], q3 = acc[mf][10][j], q4 = acc[mf][11][j];
        float* od = orow + 7168 + v5 * 288 + v31 * 3;
        // cg(1,1,1) = -eps/sqrt(6) (reference SVD sign); symmetric terms unchanged
        stnt(od + 0,   s - q2 * c30 - q4 * c10);     // D[0][0]
        stnt(od + 1,   -e2 * c6 + q1 * c10);         // D[0][1]
        stnt(od + 2,   e1 * c6 + q0 * c10);          // D[0][2]
        stnt(od + 96,  e2 * c6 + q1 * c10);          // D[1][0]
        stnt(od + 97,  s + 2.0f * q2 * c30);         // D[1][1]
        stnt(od + 98,  -e0 * c6 + q3 * c10);         // D[1][2]
        stnt(od + 192, -e1 * c6 + q0 * c10);         // D[2][0]
        stnt(od + 193, e0 * c6 + q3 * c10);          // D[2][1]
        stnt(od + 194, s - q2 * c30 + q4 * c10);     // D[2][2]
      }
    }
  } else {
    // ---- region H: v' = v-1024; y0[v] -> A block, y1o[v,:] -> B block
    const int vtp = vt - 64;
    f32x4 acc[2][4];
#pragma unroll
    for (int mf = 0; mf < 2; ++mf)
#pragma unroll
      for (int p = 0; p < 4; ++p) acc[mf][p] = (f32x4)(0.0f);

    const int ci0 = 64 + vtp, ci1 = 192 + vtp;
#pragma unroll
    for (int kb = 0; kb < 4; ++kb) {
      bf16x8 b0 = asbf(Bp[((ci0 << 2) + kb) * 64 + l]);
      bf16x8 b1 = asbf(Bp[((ci1 << 2) + kb) * 64 + l]);
#pragma unroll
      for (int mf = 0; mf < 2; ++mf) {
        const u16x8* ar = Ap + (((((mt2 << 1) | mf) << 2) + kb) << 6) + l;
        acc[mf][0] = mfma16(asbf(ar[0]),            b0, acc[mf][0]);
        acc[mf][1] = mfma16(asbf(ar[1 * P_STRIDE]), b1, acc[mf][1]);
        acc[mf][2] = mfma16(asbf(ar[2 * P_STRIDE]), b1, acc[mf][2]);
        acc[mf][3] = mfma16(asbf(ar[3 * P_STRIDE]), b1, acc[mf][3]);
      }
    }
    const int vp = vtp * 16 + l15;
#pragma unroll
    for (int mf = 0; mf < 2; ++mf) {
#pragma unroll
      for (int j = 0; j < 4; ++j) {
        const int m = mt2 * 32 + mf * 16 + lhi * 4 + j;
        float* orow = out + (size_t)m * 16384;
        stnt(orow + vp, acc[mf][0][j]);          // A block (cg = 1)
        float* ob = orow + 1024 + vp * 3;        // B block
        stnt(ob + 0, acc[mf][1][j] * c3);
        stnt(ob + 1, acc[mf][2][j] * c3);
        stnt(ob + 2, acc[mf][3][j] * c3);
      }
    }
  }
}

extern "C" void kernel_launch(void* const* d_in, const int* in_sizes, int n_in,
                              void* d_out, int out_size, void* d_ws, size_t ws_size,
                              hipStream_t stream) {
  if (ws_size < WS_NEED_BYTES) return;  // need 26.7 MB scratch; fail visibly if absent
  const float* x   = (const float*)d_in[0];
  const float* w0e = (const float*)d_in[1];
  const float* w1o = (const float*)d_in[2];
  const float* w1e = (const float*)d_in[3];
  const float* w2e = (const float*)d_in[4];
  u16x8* ws = (u16x8*)d_ws;
  float* out = (float*)d_out;

  // prep: (A_V8_TOTAL + B_V8_TOTAL) threads = 1,671,168 = 6528 * 256 exactly
  prep_kernel<<<6528, 256, 0, stream>>>(x, w0e, w1o, w1e, w2e, ws);
  // main: 256 mt2-tiles * 32 vt-blocks = 8192 blocks of 4 waves
  tp_main<<<8192, 256, 0, stream>>>(ws, out);
}